// Round 5
// baseline (285.666 us; speedup 1.0000x reference)
//
#include <hip/hip_runtime.h>
#include <hip/hip_fp16.h>

#define N_NODES 100000
#define N_EDGES 1600000
#define N_BUCKETS 256
#define BUCKET_NODES 391      // 256*391 = 100096 >= N_NODES
#define BKT_BLOCKS 512
#define CAP_E 8192            // raw edges per bucket: mean 6250
#define CAP_C 12288           // padded(8) col slots per bucket: mean ~7800
#define DUMMY N_NODES         // zero feature row (byte offset DUMMY*128)

typedef unsigned short u16;
typedef _Float16 f16x8 __attribute__((ext_vector_type(8)));
typedef float f32x4 __attribute__((ext_vector_type(4)));
typedef unsigned u32x4 __attribute__((ext_vector_type(4)));

__device__ __forceinline__ u16 f2h(float f) {
    return __half_as_ushort(__float2half_rn(f));
}

// forced-issue 16B gather: volatile asm keeps program order among loads and
// pins the destination registers live -> true deep MLP per wave.
__device__ __forceinline__ u32x4 gload16(const char* addr) {
    u32x4 d;
    asm volatile("global_load_dwordx4 %0, %1, off" : "=v"(d) : "v"(addr));
    return d;
}

__device__ __forceinline__ void acc8v(float* acc, u32x4 q) {
#pragma unroll
    for (int i = 0; i < 4; ++i) {
        unsigned w = q[i];
        __half2 h = *reinterpret_cast<__half2*>(&w);
        float2 f = __half22float2(h);
        acc[2 * i] += f.x;
        acc[2 * i + 1] += f.y;
    }
}

__device__ __forceinline__ void acc8(float* acc, uint4 q) {
    unsigned v[4] = {q.x, q.y, q.z, q.w};
#pragma unroll
    for (int i = 0; i < 4; ++i) {
        __half2 h = *reinterpret_cast<__half2*>(&v[i]);
        float2 f = __half22float2(h);
        acc[2 * i] += f.x;
        acc[2 * i + 1] += f.y;
    }
}

// ---- phase 1: bucket edges into CONTIGUOUS per-bucket runs (R8 form).
//      Blocks >= BKT_BLOCKS instead do the one-time W fragment permute:
//      Wp[t][c][quad][l16][j] = fp16(W[quad*8+32c+j][4*l16+t]). ----
__global__ __launch_bounds__(256) void k_bucket(const int* __restrict__ src,
                                                const int* __restrict__ dst,
                                                int* __restrict__ btot,
                                                int* __restrict__ ebuf,
                                                const float* __restrict__ W1,
                                                const float* __restrict__ W2,
                                                const float* __restrict__ W3,
                                                u16* __restrict__ Wp) {
    __shared__ int cnt[N_BUCKETS], base_s[N_BUCKETS];
    if (blockIdx.x >= BKT_BLOCKS) {  // fused k_prepw
        int wb = blockIdx.x - BKT_BLOCKS;
        const float* W = wb == 0 ? W1 : (wb == 1 ? W2 : W3);
        u16* o = Wp + wb * 4096;
        for (int f = threadIdx.x; f < 4096; f += 256) {
            int j = f & 7, l16 = (f >> 3) & 15, quad = (f >> 7) & 3;
            int c = (f >> 9) & 1, t = f >> 10;
            o[f] = f2h(W[(quad * 8 + 32 * c + j) * 64 + 4 * l16 + t]);
        }
        return;
    }
    const int CS = N_EDGES / BKT_BLOCKS;  // 3125
    int t = threadIdx.x;
    int beg = blockIdx.x * CS, end = beg + CS;
    for (int i = t; i < N_BUCKETS; i += 256) cnt[i] = 0;
    __syncthreads();
    for (int e = beg + t; e < end; e += 256)
        atomicAdd(&cnt[(unsigned)dst[e] / BUCKET_NODES], 1);
    __syncthreads();
    for (int i = t; i < N_BUCKETS; i += 256) {
        base_s[i] = atomicAdd(&btot[i], cnt[i]);
        cnt[i] = 0;  // reuse as local cursor
    }
    __syncthreads();
    for (int e = beg + t; e < end; e += 256) {
        int d = dst[e], s = src[e];
        int b = (unsigned)d / BUCKET_NODES;
        int l = atomicAdd(&cnt[b], 1);
        ebuf[b * CAP_E + base_s[b] + l] = s | ((d - b * BUCKET_NODES) << 17);
    }
}

// ---- phase 2: per-bucket LDS bin; PAD-8 rows; col = byte offsets; 16-entry
//      DUMMY guard after each bucket's run; fused xs(fp16) = z*dinv. ----
__global__ __launch_bounds__(1024) void k_build(const int* __restrict__ btot,
                                                const int* __restrict__ ebuf,
                                                int* __restrict__ col,
                                                int2* __restrict__ rowinfo,
                                                float* __restrict__ dinv,
                                                const float* __restrict__ z,
                                                u16* __restrict__ xs,
                                                u16* __restrict__ xs_other) {
    __shared__ int deg[BUCKET_NODES];
    __shared__ int cur[BUCKET_NODES];
    __shared__ int sm[512];
    __shared__ int cls[CAP_C];
    int b = blockIdx.x, t = threadIdx.x;
    int nb = b * BUCKET_NODES;
    int nn = N_NODES - nb < BUCKET_NODES ? N_NODES - nb : BUCKET_NODES;
    int ne = btot[b];
    const int* eb = ebuf + b * CAP_E;

    for (int i = t; i < BUCKET_NODES; i += 1024) deg[i] = 0;
    __syncthreads();
    for (int e = t; e < ne; e += 1024) atomicAdd(&deg[eb[e] >> 17], 1);
    __syncthreads();

    // pad-to-8 lengths, inclusive Hillis-Steele scan over 512 slots (nn<512)
    int v = (t < nn) ? ((deg[t] + 7) & ~7) : 0;
    if (t < 512) sm[t] = v;
    __syncthreads();
    for (int off = 1; off < 512; off <<= 1) {
        int u = (t >= off && t < 512) ? sm[t - off] : 0;
        __syncthreads();
        if (t < 512) sm[t] += u;
        __syncthreads();
    }
    int total = sm[511];
    int colbase = b * CAP_C;
    if (t < nn) {
        int off0 = sm[t] - v;
        cur[t] = off0;
        rowinfo[nb + t] = make_int2(colbase + off0, v);
        dinv[nb + t] = rsqrtf((float)deg[t] + 1.0f);
    }
    __syncthreads();
    for (int i = t; i < total; i += 1024) cls[i] = DUMMY << 7;  // pads pre-filled
    __syncthreads();
    for (int e = t; e < ne; e += 1024) {
        int pe = eb[e];
        int l = atomicAdd(&cur[pe >> 17], 1);
        cls[l] = (pe & 0x1FFFF) << 7;  // byte offset of src row
    }
    __syncthreads();
    for (int i = t; i < total; i += 1024) col[colbase + i] = cls[i];
    if (t < 16) col[colbase + total + t] = DUMMY << 7;  // guard for clamped reads

    // fused scale: xs(fp16) = z * dinv for this bucket's rows
    const float4* zz = (const float4*)(z + (size_t)nb * 64);
    uint2* xx = (uint2*)(xs + (size_t)nb * 64);
    for (int i = t; i < nn * 16; i += 1024) {
        float4 vv = zz[i];
        float dd = rsqrtf((float)deg[i >> 4] + 1.0f);
        unsigned p0 = (unsigned)f2h(vv.x * dd) | ((unsigned)f2h(vv.y * dd) << 16);
        unsigned p1 = (unsigned)f2h(vv.z * dd) | ((unsigned)f2h(vv.w * dd) << 16);
        xx[i] = make_uint2(p0, p1);
    }
    if (b == 0 && t < 8) {  // zero dummy rows of both fp16 feature buffers
        ((uint4*)(xs + (size_t)N_NODES * 64))[t] = make_uint4(0, 0, 0, 0);
        ((uint4*)(xs_other + (size_t)N_NODES * 64))[t] = make_uint4(0, 0, 0, 0);
    }
}

// ---- FUSED aggregation + matvec, QUAD-node waves.
//      agg: p[n] = fp16( dinv[n]*(sum_{s in row(n)} xs[s] + xs[n]) ), kept in
//      registers. Compacted issue: 8 main gathers + tail gathers only when the
//      node has a tail chunk (wave-uniform branch) + ONE self instr (eighth&3
//      addressing). Then the MFMA matvec runs in-register: A-frag built via
//      8 shfls (dest (quad,l16) pulls p_{l16} dims quad*8+j from src lane
//      (l16<<3)|quad; rows l16>=4 zeroed), B frags column-permuted from Wp
//      (register t owns output column 4*l16+t). Epilogue (quad==0 lanes) does
//      bias (+relu*dinv for hidden) and stores features/output directly —
//      no h round-trip, no separate k_mv. ----
__global__ __launch_bounds__(256, 3) void k_fused(const int2* __restrict__ rowinfo,
                                                  const int* __restrict__ col,
                                                  const float* __restrict__ dinv,
                                                  const u16* __restrict__ xs,
                                                  const u16* __restrict__ Wp,
                                                  const float* __restrict__ bias,
                                                  u16* __restrict__ outh,
                                                  float* __restrict__ outf,
                                                  int hidden) {
    const int lane = threadIdx.x & 63;
    const int eighth = lane >> 3;
    const int fh = lane & 7;
    const int l16 = lane & 15;
    const int quad = lane >> 4;
    const char* xb = (const char*)xs;

    // B fragments + bias (persistent)
    const uint4* wq = (const uint4*)Wp;
    union { uint4 u; f16x8 f; } bfr[4][2];
#pragma unroll
    for (int t = 0; t < 4; ++t)
#pragma unroll
        for (int c = 0; c < 2; ++c)
            bfr[t][c].u = wq[t * 128 + c * 64 + quad * 16 + l16];
    float4 bq = ((const float4*)bias)[l16];

    int wave = (blockIdx.x * blockDim.x + threadIdx.x) >> 6;
    int nwaves = (gridDim.x * blockDim.x) >> 6;

    for (int n0 = wave * 4; n0 < N_NODES; n0 += nwaves * 4) {
        int u0 = __builtin_amdgcn_readfirstlane(n0);  // uniform -> s_loads below
        int2 r0 = rowinfo[u0];
        int2 r1 = rowinfo[u0 + 1];
        int2 r2 = rowinfo[u0 + 2];
        int2 r3 = rowinfo[u0 + 3];
        int it0 = r0.y >> 4, it1 = r1.y >> 4, it2 = r2.y >> 4, it3 = r3.y >> 4;
        int itm = it0 > it1 ? it0 : it1;
        if (it2 > itm) itm = it2;
        if (it3 > itm) itm = it3;
        int t0 = (r0.y >> 3) & 1, t1 = (r1.y >> 3) & 1;
        int t2 = (r2.y >> 3) & 1, t3 = (r3.y >> 3) & 1;

        // iter-0 cols + tail cols (guard slots make every address safe)
        int2 c0 = *(const int2*)(col + r0.x + 2 * eighth);
        int2 c1 = *(const int2*)(col + r1.x + 2 * eighth);
        int2 c2 = *(const int2*)(col + r2.x + 2 * eighth);
        int2 c3 = *(const int2*)(col + r3.x + 2 * eighth);
        int tc0 = col[r0.x + (it0 << 4) + eighth];
        int tc1 = col[r1.x + (it1 << 4) + eighth];
        int tc2 = col[r2.x + (it2 << 4) + eighth];
        int tc3 = col[r3.x + (it3 << 4) + eighth];
        float d0 = dinv[u0];
        float d1 = dinv[u0 + 1];
        float d2 = dinv[u0 + 2];
        float d3 = dinv[u0 + 3];

        // ---- compacted deep issue: 8 main + conditional tails + 1 self ----
        u32x4 q0 = gload16(xb + (unsigned)c0.x + fh * 16);
        u32x4 q1 = gload16(xb + (unsigned)c0.y + fh * 16);
        u32x4 q2 = gload16(xb + (unsigned)c1.x + fh * 16);
        u32x4 q3 = gload16(xb + (unsigned)c1.y + fh * 16);
        u32x4 q4 = gload16(xb + (unsigned)c2.x + fh * 16);
        u32x4 q5 = gload16(xb + (unsigned)c2.y + fh * 16);
        u32x4 q6 = gload16(xb + (unsigned)c3.x + fh * 16);
        u32x4 q7 = gload16(xb + (unsigned)c3.y + fh * 16);
        u32x4 g0 = {0, 0, 0, 0}, g1 = {0, 0, 0, 0};
        u32x4 g2 = {0, 0, 0, 0}, g3 = {0, 0, 0, 0};
        if (t0) g0 = gload16(xb + (unsigned)tc0 + fh * 16);
        if (t1) g1 = gload16(xb + (unsigned)tc1 + fh * 16);
        if (t2) g2 = gload16(xb + (unsigned)tc2 + fh * 16);
        if (t3) g3 = gload16(xb + (unsigned)tc3 + fh * 16);
        u32x4 sf = gload16(xb + (size_t)(u0 + (eighth & 3)) * 128 + fh * 16);
        asm volatile("s_waitcnt vmcnt(0)" ::: "memory");
        __builtin_amdgcn_sched_barrier(0);  // consumes stay below

        float a0[8] = {0.f, 0.f, 0.f, 0.f, 0.f, 0.f, 0.f, 0.f};
        float a1[8] = {0.f, 0.f, 0.f, 0.f, 0.f, 0.f, 0.f, 0.f};
        float a2[8] = {0.f, 0.f, 0.f, 0.f, 0.f, 0.f, 0.f, 0.f};
        float a3[8] = {0.f, 0.f, 0.f, 0.f, 0.f, 0.f, 0.f, 0.f};
        if (0 < it0) { acc8v(a0, q0); acc8v(a0, q1); }
        if (0 < it1) { acc8v(a1, q2); acc8v(a1, q3); }
        if (0 < it2) { acc8v(a2, q4); acc8v(a2, q5); }
        if (0 < it3) { acc8v(a3, q6); acc8v(a3, q7); }
        if (t0) acc8v(a0, g0);
        if (t1) acc8v(a1, g1);
        if (t2) acc8v(a2, g2);
        if (t3) acc8v(a3, g3);
        if (eighth == 0) acc8v(a0, sf);
        if (eighth == 1) acc8v(a1, sf);
        if (eighth == 2) acc8v(a2, sf);
        if (eighth == 3) acc8v(a3, sf);

        // rare path: remaining 16-slot iterations (itm > 1 for ~6% of quads)
        for (int rr = 1; rr < itm; ++rr) {
            int2 e0 = *(const int2*)(col + r0.x + ((rr < it0 ? rr : 0) << 4) + 2 * eighth);
            int2 e1 = *(const int2*)(col + r1.x + ((rr < it1 ? rr : 0) << 4) + 2 * eighth);
            int2 e2 = *(const int2*)(col + r2.x + ((rr < it2 ? rr : 0) << 4) + 2 * eighth);
            int2 e3 = *(const int2*)(col + r3.x + ((rr < it3 ? rr : 0) << 4) + 2 * eighth);
            uint4 p0 = *(const uint4*)(xb + (unsigned)e0.x + fh * 16);
            uint4 p1 = *(const uint4*)(xb + (unsigned)e0.y + fh * 16);
            uint4 p2 = *(const uint4*)(xb + (unsigned)e1.x + fh * 16);
            uint4 p3 = *(const uint4*)(xb + (unsigned)e1.y + fh * 16);
            uint4 p4 = *(const uint4*)(xb + (unsigned)e2.x + fh * 16);
            uint4 p5 = *(const uint4*)(xb + (unsigned)e2.y + fh * 16);
            uint4 p6 = *(const uint4*)(xb + (unsigned)e3.x + fh * 16);
            uint4 p7 = *(const uint4*)(xb + (unsigned)e3.y + fh * 16);
            if (rr < it0) { acc8(a0, p0); acc8(a0, p1); }
            if (rr < it1) { acc8(a1, p2); acc8(a1, p3); }
            if (rr < it2) { acc8(a2, p4); acc8(a2, p5); }
            if (rr < it3) { acc8(a3, p6); acc8(a3, p7); }
        }

#pragma unroll
        for (int m = 8; m <= 32; m <<= 1) {
#pragma unroll
            for (int j = 0; j < 8; ++j) {
                a0[j] += __shfl_xor(a0[j], m, 64);
                a1[j] += __shfl_xor(a1[j], m, 64);
                a2[j] += __shfl_xor(a2[j], m, 64);
                a3[j] += __shfl_xor(a3[j], m, 64);
            }
        }
        // pack normalized rows: p_k = fp16x8 of h[u_k][fh*8 .. fh*8+7]
        uint4 p0, p1, p2, p3;
        u16* pp0 = (u16*)&p0;
        u16* pp1 = (u16*)&p1;
        u16* pp2 = (u16*)&p2;
        u16* pp3 = (u16*)&p3;
#pragma unroll
        for (int j = 0; j < 8; ++j) {
            pp0[j] = f2h(a0[j] * d0);
            pp1[j] = f2h(a1[j] * d1);
            pp2[j] = f2h(a2[j] * d2);
            pp3[j] = f2h(a3[j] * d3);
        }

        // ---- in-register matvec: A-frag via shfl ----
        int e3i = eighth & 3;
        uint4 pa;
        pa.x = e3i == 0 ? p0.x : e3i == 1 ? p1.x : e3i == 2 ? p2.x : p3.x;
        pa.y = e3i == 0 ? p0.y : e3i == 1 ? p1.y : e3i == 2 ? p2.y : p3.y;
        pa.z = e3i == 0 ? p0.z : e3i == 1 ? p1.z : e3i == 2 ? p2.z : p3.z;
        pa.w = e3i == 0 ? p0.w : e3i == 1 ? p1.w : e3i == 2 ? p2.w : p3.w;
        int si0 = (l16 << 3) | quad;        // src lane for k-dims quad*8+j
        int si1 = si0 | 4;                  // src lane for k-dims 32+quad*8+j
        union { uint4 u; f16x8 f; } A0, A1;
        A0.u.x = (unsigned)__shfl((int)pa.x, si0, 64);
        A0.u.y = (unsigned)__shfl((int)pa.y, si0, 64);
        A0.u.z = (unsigned)__shfl((int)pa.z, si0, 64);
        A0.u.w = (unsigned)__shfl((int)pa.w, si0, 64);
        A1.u.x = (unsigned)__shfl((int)pa.x, si1, 64);
        A1.u.y = (unsigned)__shfl((int)pa.y, si1, 64);
        A1.u.z = (unsigned)__shfl((int)pa.z, si1, 64);
        A1.u.w = (unsigned)__shfl((int)pa.w, si1, 64);
        if (l16 >= 4) {  // only rows 0..3 are real
            A0.u = make_uint4(0, 0, 0, 0);
            A1.u = make_uint4(0, 0, 0, 0);
        }
        f32x4 acc[4] = {{0.f, 0.f, 0.f, 0.f}, {0.f, 0.f, 0.f, 0.f},
                        {0.f, 0.f, 0.f, 0.f}, {0.f, 0.f, 0.f, 0.f}};
#pragma unroll
        for (int t = 0; t < 4; ++t) {
            acc[t] = __builtin_amdgcn_mfma_f32_16x16x32_f16(A0.f, bfr[t][0].f, acc[t], 0, 0, 0);
            acc[t] = __builtin_amdgcn_mfma_f32_16x16x32_f16(A1.f, bfr[t][1].f, acc[t], 0, 0, 0);
        }
        // D[row=quad*4+reg][col=4*l16+t]: rows 0..3 live in quad==0 lanes
        if (quad == 0) {
#pragma unroll
            for (int r = 0; r < 4; ++r) {
                float o0 = acc[0][r] + bq.x;
                float o1 = acc[1][r] + bq.y;
                float o2 = acc[2][r] + bq.z;
                float o3 = acc[3][r] + bq.w;
                int row = u0 + r;
                if (hidden) {
                    float dd = r == 0 ? d0 : r == 1 ? d1 : r == 2 ? d2 : d3;
                    o0 = fmaxf(o0, 0.f) * dd;
                    o1 = fmaxf(o1, 0.f) * dd;
                    o2 = fmaxf(o2, 0.f) * dd;
                    o3 = fmaxf(o3, 0.f) * dd;
                    unsigned lo = (unsigned)f2h(o0) | ((unsigned)f2h(o1) << 16);
                    unsigned hi = (unsigned)f2h(o2) | ((unsigned)f2h(o3) << 16);
                    ((uint2*)(outh + (size_t)row * 64))[l16] = make_uint2(lo, hi);
                } else {
                    ((float4*)(outf + (size_t)row * 64))[l16] =
                        make_float4(o0, o1, o2, o3);
                }
            }
        }
    }
}

extern "C" void kernel_launch(void* const* d_in, const int* in_sizes, int n_in,
                              void* d_out, int out_size, void* d_ws, size_t ws_size,
                              hipStream_t stream) {
    const float* z  = (const float*)d_in[0];
    const int* src  = (const int*)d_in[1];
    const int* dst  = (const int*)d_in[2];
    const float* W1 = (const float*)d_in[3];
    const float* b1 = (const float*)d_in[4];
    const float* W2 = (const float*)d_in[5];
    const float* b2 = (const float*)d_in[6];
    const float* W3 = (const float*)d_in[7];
    const float* b3 = (const float*)d_in[8];
    float* out = (float*)d_out;

    char* p = (char*)d_ws;
    float* dinv    = (float*)p;  p += (size_t)512 << 10;
    int2*  rowinfo = (int2*)p;   p += (size_t)1 << 20;                   // 800 KB used
    int*   btot    = (int*)p;    p += (size_t)4 << 10;                   // 1 KB used
    int*   ebuf    = (int*)p;    p += (size_t)N_BUCKETS * CAP_E * 4;     // 8 MB
    int*   col     = (int*)p;    p += (size_t)N_BUCKETS * CAP_C * 4;     // 12.6 MB
    u16*   hbuf    = (u16*)p;    p += (size_t)13 << 20;                  // (unused now)
    u16*   buf0    = (u16*)p;    p += (size_t)13 << 20;                  // +dummy row
    u16*   buf1    = (u16*)p;    p += (size_t)13 << 20;                  // +dummy row
    u16*   wp      = (u16*)p;                                            // 24 KB
    (void)hbuf;

    const int gA = 2048;  // 8192 waves, 3.05 quads each

    // ---- CSR build + W permute (fused) + fp16 scale ----
    hipMemsetAsync(btot, 0, N_BUCKETS * sizeof(int), stream);
    k_bucket<<<BKT_BLOCKS + 3, 256, 0, stream>>>(src, dst, btot, ebuf, W1, W2, W3, wp);
    k_build<<<N_BUCKETS, 1024, 0, stream>>>(btot, ebuf, col, rowinfo, dinv, z, buf0, buf1);

    // ---- 3 fused layers: gather-agg + MFMA matvec in one kernel ----
    k_fused<<<gA, 256, 0, stream>>>(rowinfo, col, dinv, buf0, wp,        b1, buf1, nullptr, 1);
    k_fused<<<gA, 256, 0, stream>>>(rowinfo, col, dinv, buf1, wp + 4096, b2, buf0, nullptr, 1);
    k_fused<<<gA, 256, 0, stream>>>(rowinfo, col, dinv, buf0, wp + 8192, b3, nullptr, out, 0);
}

// Round 6
// 257.020 us; speedup vs baseline: 1.1115x; 1.1115x over previous
//
#include <hip/hip_runtime.h>
#include <hip/hip_fp16.h>

#define N_NODES 100000
#define N_EDGES 1600000
#define N_BUCKETS 512
#define BUCKET_NODES 196      // 512*196 = 100352 >= N_NODES
#define BKT_BLOCKS 512
#define CAP_E 4096            // raw edges per bucket: mean 3125 (17 sigma slack)
#define CAP_C 6144            // padded(8) col slots per bucket: mean ~3920
#define DUMMY N_NODES         // zero feature row (byte offset DUMMY*128)

typedef unsigned short u16;
typedef _Float16 f16x8 __attribute__((ext_vector_type(8)));
typedef float f32x4 __attribute__((ext_vector_type(4)));
typedef unsigned u32x4 __attribute__((ext_vector_type(4)));

__device__ __forceinline__ u16 f2h(float f) {
    return __half_as_ushort(__float2half_rn(f));
}

// forced-issue 16B gather: volatile asm keeps program order among loads and
// pins the destination registers live -> true deep MLP per wave.
__device__ __forceinline__ u32x4 gload16(const char* addr) {
    u32x4 d;
    asm volatile("global_load_dwordx4 %0, %1, off" : "=v"(d) : "v"(addr));
    return d;
}

__device__ __forceinline__ void acc8v(float* acc, u32x4 q) {
#pragma unroll
    for (int i = 0; i < 4; ++i) {
        unsigned w = q[i];
        __half2 h = *reinterpret_cast<__half2*>(&w);
        float2 f = __half22float2(h);
        acc[2 * i] += f.x;
        acc[2 * i + 1] += f.y;
    }
}

__device__ __forceinline__ void acc8(float* acc, uint4 q) {
    unsigned v[4] = {q.x, q.y, q.z, q.w};
#pragma unroll
    for (int i = 0; i < 4; ++i) {
        __half2 h = *reinterpret_cast<__half2*>(&v[i]);
        float2 f = __half22float2(h);
        acc[2 * i] += f.x;
        acc[2 * i + 1] += f.y;
    }
}

// ---- phase 1: bucket edges into CONTIGUOUS per-bucket runs (R8 form).
//      Blocks >= BKT_BLOCKS instead do the one-time W fragment permute:
//      Wp[t][c][quad][l16][j] = fp16(W[quad*8+32c+j][4*l16+t]). ----
__global__ __launch_bounds__(256) void k_bucket(const int* __restrict__ src,
                                                const int* __restrict__ dst,
                                                int* __restrict__ btot,
                                                int* __restrict__ ebuf,
                                                const float* __restrict__ W1,
                                                const float* __restrict__ W2,
                                                const float* __restrict__ W3,
                                                u16* __restrict__ Wp) {
    __shared__ int cnt[N_BUCKETS], base_s[N_BUCKETS];
    if (blockIdx.x >= BKT_BLOCKS) {  // fused k_prepw
        int wb = blockIdx.x - BKT_BLOCKS;
        const float* W = wb == 0 ? W1 : (wb == 1 ? W2 : W3);
        u16* o = Wp + wb * 4096;
        for (int f = threadIdx.x; f < 4096; f += 256) {
            int j = f & 7, l16 = (f >> 3) & 15, quad = (f >> 7) & 3;
            int c = (f >> 9) & 1, t = f >> 10;
            o[f] = f2h(W[(quad * 8 + 32 * c + j) * 64 + 4 * l16 + t]);
        }
        return;
    }
    const int CS = N_EDGES / BKT_BLOCKS;  // 3125
    int t = threadIdx.x;
    int beg = blockIdx.x * CS, end = beg + CS;
    for (int i = t; i < N_BUCKETS; i += 256) cnt[i] = 0;
    __syncthreads();
    for (int e = beg + t; e < end; e += 256)
        atomicAdd(&cnt[(unsigned)dst[e] / BUCKET_NODES], 1);
    __syncthreads();
    for (int i = t; i < N_BUCKETS; i += 256) {
        base_s[i] = atomicAdd(&btot[i], cnt[i]);
        cnt[i] = 0;  // reuse as local cursor
    }
    __syncthreads();
    for (int e = beg + t; e < end; e += 256) {
        int d = dst[e], s = src[e];
        int b = (unsigned)d / BUCKET_NODES;
        int l = atomicAdd(&cnt[b], 1);
        ebuf[b * CAP_E + base_s[b] + l] = s | ((d - b * BUCKET_NODES) << 17);
    }
}

// ---- phase 2: per-bucket LDS bin; PAD-8 rows; col = byte offsets; 16-entry
//      DUMMY guard after each bucket's run; fused xs(fp16) = z*dinv.
//      512 buckets x 512 threads (2 blocks/CU), wave-shuffle scan (1 barrier
//      instead of 18) — parallelized vs the old 256x1024 version. ----
__global__ __launch_bounds__(512) void k_build(const int* __restrict__ btot,
                                               const int* __restrict__ ebuf,
                                               int* __restrict__ col,
                                               int2* __restrict__ rowinfo,
                                               float* __restrict__ dinv,
                                               const float* __restrict__ z,
                                               u16* __restrict__ xs,
                                               u16* __restrict__ xs_other) {
    __shared__ int deg[BUCKET_NODES];
    __shared__ int cur[BUCKET_NODES];
    __shared__ int wsum[4];
    __shared__ int cls[CAP_C];
    int b = blockIdx.x, t = threadIdx.x;
    int nb = b * BUCKET_NODES;
    int nn = N_NODES - nb;
    if (nn > BUCKET_NODES) nn = BUCKET_NODES;
    int ne = btot[b];
    const int* eb = ebuf + b * CAP_E;

    for (int i = t; i < BUCKET_NODES; i += 512) deg[i] = 0;
    __syncthreads();
    for (int e = t; e < ne; e += 512) atomicAdd(&deg[eb[e] >> 17], 1);
    __syncthreads();

    // pad-to-8 lengths; inclusive wave-shuffle scan over 256 slots (nn<=196)
    int pv = (t < nn) ? ((deg[t] + 7) & ~7) : 0;
    int v = pv;
    int lane = t & 63, wv = t >> 6;
#pragma unroll
    for (int off = 1; off < 64; off <<= 1) {
        int u = __shfl_up(v, off, 64);
        if (lane >= off) v += u;
    }
    if (t < 256 && lane == 63) wsum[wv] = v;
    __syncthreads();
    int total = wsum[0] + wsum[1] + wsum[2] + wsum[3];
    int add = 0;
    for (int i = 0; i < wv && i < 4; ++i) add += wsum[i];
    int incl = v + add;  // inclusive scan value for slot t (t<256)

    int colbase = b * CAP_C;
    if (t < nn) {
        int off0 = incl - pv;
        cur[t] = off0;
        rowinfo[nb + t] = make_int2(colbase + off0, pv);
        dinv[nb + t] = rsqrtf((float)deg[t] + 1.0f);
    }
    __syncthreads();
    for (int i = t; i < total; i += 512) cls[i] = DUMMY << 7;  // pads pre-filled
    __syncthreads();
    for (int e = t; e < ne; e += 512) {
        int pe = eb[e];
        int l = atomicAdd(&cur[pe >> 17], 1);
        cls[l] = (pe & 0x1FFFF) << 7;  // byte offset of src row
    }
    __syncthreads();
    for (int i = t; i < total; i += 512) col[colbase + i] = cls[i];
    if (t < 16) col[colbase + total + t] = DUMMY << 7;  // guard for clamped reads

    // fused scale: xs(fp16) = z * dinv for this bucket's rows
    const float4* zz = (const float4*)(z + (size_t)nb * 64);
    uint2* xx = (uint2*)(xs + (size_t)nb * 64);
    for (int i = t; i < nn * 16; i += 512) {
        float4 vv = zz[i];
        float dd = rsqrtf((float)deg[i >> 4] + 1.0f);
        unsigned p0 = (unsigned)f2h(vv.x * dd) | ((unsigned)f2h(vv.y * dd) << 16);
        unsigned p1 = (unsigned)f2h(vv.z * dd) | ((unsigned)f2h(vv.w * dd) << 16);
        xx[i] = make_uint2(p0, p1);
    }
    if (b == 0 && t < 8) {  // zero dummy rows of both fp16 feature buffers
        ((uint4*)(xs + (size_t)N_NODES * 64))[t] = make_uint4(0, 0, 0, 0);
        ((uint4*)(xs_other + (size_t)N_NODES * 64))[t] = make_uint4(0, 0, 0, 0);
    }
}

// ---- gather-only aggregation, pad-8 rows, QUAD-node waves, FORCED 16-deep
//      issue via inline-asm global_load_dwordx4 (volatile order + live dests)
//      + single s_waitcnt vmcnt(0) + sched_barrier(0). Grid sized so each
//      wave owns exactly ONE quad (no cross-quad drain serialization).
//      h[n] = fp16( dinv[n]*(sum_{s in row(n)} xs[s] + xs[n]) ). ----
__global__ __launch_bounds__(256, 3) void k_agg(const int2* __restrict__ rowinfo,
                                                const int* __restrict__ col,
                                                const float* __restrict__ dinv,
                                                const u16* __restrict__ xs,
                                                u16* __restrict__ h) {
    const int lane = threadIdx.x & 63;
    const int eighth = lane >> 3;
    const int fh = lane & 7;
    const char* xb = (const char*)xs;
    int wave = (blockIdx.x * blockDim.x + threadIdx.x) >> 6;
    int nwaves = (gridDim.x * blockDim.x) >> 6;

    for (int n0 = wave * 4; n0 < N_NODES; n0 += nwaves * 4) {
        int u0 = __builtin_amdgcn_readfirstlane(n0);  // uniform -> s_loads below
        int2 r0 = rowinfo[u0];
        int2 r1 = rowinfo[u0 + 1];
        int2 r2 = rowinfo[u0 + 2];
        int2 r3 = rowinfo[u0 + 3];
        int it0 = r0.y >> 4, it1 = r1.y >> 4, it2 = r2.y >> 4, it3 = r3.y >> 4;
        int itm = it0 > it1 ? it0 : it1;
        if (it2 > itm) itm = it2;
        if (it3 > itm) itm = it3;

        // iter-0 cols + tail cols (guard slots make every address safe)
        int2 c0 = *(const int2*)(col + r0.x + 2 * eighth);
        int2 c1 = *(const int2*)(col + r1.x + 2 * eighth);
        int2 c2 = *(const int2*)(col + r2.x + 2 * eighth);
        int2 c3 = *(const int2*)(col + r3.x + 2 * eighth);
        int tc0 = col[r0.x + (it0 << 4) + eighth];
        int tc1 = col[r1.x + (it1 << 4) + eighth];
        int tc2 = col[r2.x + (it2 << 4) + eighth];
        int tc3 = col[r3.x + (it3 << 4) + eighth];
        float d0 = dinv[u0];
        float d1 = dinv[u0 + 1];
        float d2 = dinv[u0 + 2];
        float d3 = dinv[u0 + 3];

        // ---- forced 16-deep issue: 8 main + 4 tail + 4 self ----
        u32x4 q0 = gload16(xb + (unsigned)c0.x + fh * 16);
        u32x4 q1 = gload16(xb + (unsigned)c0.y + fh * 16);
        u32x4 q2 = gload16(xb + (unsigned)c1.x + fh * 16);
        u32x4 q3 = gload16(xb + (unsigned)c1.y + fh * 16);
        u32x4 q4 = gload16(xb + (unsigned)c2.x + fh * 16);
        u32x4 q5 = gload16(xb + (unsigned)c2.y + fh * 16);
        u32x4 q6 = gload16(xb + (unsigned)c3.x + fh * 16);
        u32x4 q7 = gload16(xb + (unsigned)c3.y + fh * 16);
        u32x4 g0 = gload16(xb + (unsigned)tc0 + fh * 16);
        u32x4 g1 = gload16(xb + (unsigned)tc1 + fh * 16);
        u32x4 g2 = gload16(xb + (unsigned)tc2 + fh * 16);
        u32x4 g3 = gload16(xb + (unsigned)tc3 + fh * 16);
        u32x4 s0 = gload16(xb + (size_t)u0 * 128 + fh * 16);
        u32x4 s1 = gload16(xb + (size_t)(u0 + 1) * 128 + fh * 16);
        u32x4 s2 = gload16(xb + (size_t)(u0 + 2) * 128 + fh * 16);
        u32x4 s3 = gload16(xb + (size_t)(u0 + 3) * 128 + fh * 16);
        asm volatile("s_waitcnt vmcnt(0)" ::: "memory");
        __builtin_amdgcn_sched_barrier(0);  // nothing crosses: consumes stay below

        float a0[8] = {0.f, 0.f, 0.f, 0.f, 0.f, 0.f, 0.f, 0.f};
        float a1[8] = {0.f, 0.f, 0.f, 0.f, 0.f, 0.f, 0.f, 0.f};
        float a2[8] = {0.f, 0.f, 0.f, 0.f, 0.f, 0.f, 0.f, 0.f};
        float a3[8] = {0.f, 0.f, 0.f, 0.f, 0.f, 0.f, 0.f, 0.f};
        if (0 < it0) { acc8v(a0, q0); acc8v(a0, q1); }
        if (0 < it1) { acc8v(a1, q2); acc8v(a1, q3); }
        if (0 < it2) { acc8v(a2, q4); acc8v(a2, q5); }
        if (0 < it3) { acc8v(a3, q6); acc8v(a3, q7); }
        if ((r0.y >> 3) & 1) acc8v(a0, g0);
        if ((r1.y >> 3) & 1) acc8v(a1, g1);
        if ((r2.y >> 3) & 1) acc8v(a2, g2);
        if ((r3.y >> 3) & 1) acc8v(a3, g3);
        if (eighth == 0) acc8v(a0, s0);
        if (eighth == 1) acc8v(a1, s1);
        if (eighth == 2) acc8v(a2, s2);
        if (eighth == 3) acc8v(a3, s3);

        // rare path: remaining 16-slot iterations (itm > 1 for ~6% of quads)
        for (int rr = 1; rr < itm; ++rr) {
            int2 e0 = *(const int2*)(col + r0.x + ((rr < it0 ? rr : 0) << 4) + 2 * eighth);
            int2 e1 = *(const int2*)(col + r1.x + ((rr < it1 ? rr : 0) << 4) + 2 * eighth);
            int2 e2 = *(const int2*)(col + r2.x + ((rr < it2 ? rr : 0) << 4) + 2 * eighth);
            int2 e3 = *(const int2*)(col + r3.x + ((rr < it3 ? rr : 0) << 4) + 2 * eighth);
            uint4 p0 = *(const uint4*)(xb + (unsigned)e0.x + fh * 16);
            uint4 p1 = *(const uint4*)(xb + (unsigned)e0.y + fh * 16);
            uint4 p2 = *(const uint4*)(xb + (unsigned)e1.x + fh * 16);
            uint4 p3 = *(const uint4*)(xb + (unsigned)e1.y + fh * 16);
            uint4 p4 = *(const uint4*)(xb + (unsigned)e2.x + fh * 16);
            uint4 p5 = *(const uint4*)(xb + (unsigned)e2.y + fh * 16);
            uint4 p6 = *(const uint4*)(xb + (unsigned)e3.x + fh * 16);
            uint4 p7 = *(const uint4*)(xb + (unsigned)e3.y + fh * 16);
            if (rr < it0) { acc8(a0, p0); acc8(a0, p1); }
            if (rr < it1) { acc8(a1, p2); acc8(a1, p3); }
            if (rr < it2) { acc8(a2, p4); acc8(a2, p5); }
            if (rr < it3) { acc8(a3, p6); acc8(a3, p7); }
        }

#pragma unroll
        for (int m = 8; m <= 32; m <<= 1) {
#pragma unroll
            for (int j = 0; j < 8; ++j) {
                a0[j] += __shfl_xor(a0[j], m, 64);
                a1[j] += __shfl_xor(a1[j], m, 64);
                a2[j] += __shfl_xor(a2[j], m, 64);
                a3[j] += __shfl_xor(a3[j], m, 64);
            }
        }
        uint4 p0, p1, p2, p3;
        u16* pp0 = (u16*)&p0;
        u16* pp1 = (u16*)&p1;
        u16* pp2 = (u16*)&p2;
        u16* pp3 = (u16*)&p3;
#pragma unroll
        for (int j = 0; j < 8; ++j) {
            pp0[j] = f2h(a0[j] * d0);
            pp1[j] = f2h(a1[j] * d1);
            pp2[j] = f2h(a2[j] * d2);
            pp3[j] = f2h(a3[j] * d3);
        }
        if (eighth == 0) ((uint4*)(h + (size_t)u0 * 64))[fh] = p0;
        if (eighth == 1) ((uint4*)(h + (size_t)(u0 + 1) * 64))[fh] = p1;
        if (eighth == 2) ((uint4*)(h + (size_t)(u0 + 2) * 64))[fh] = p2;
        if (eighth == 3) ((uint4*)(h + (size_t)(u0 + 3) * 64))[fh] = p3;
    }
}

// ---- MFMA matvec: out = epi( h @ W + b ), 16-row chunks per wave.
//      mfma_f32_16x16x32_f16: A[m=lane&15][k=quad*8+j], B[k=quad*8+j][n=lane&15],
//      D[row=quad*4+reg][col=lane&15]. B fragments COLUMN-PERMUTED (register t
//      owns output column 4*l16+t) and PRELOADED from Wp: one 8B (fp16) /
//      16B (f32) store per row-slice. Output memory layout canonical. ----
__global__ __launch_bounds__(256) void k_mv(const u16* __restrict__ h,
                                            const u16* __restrict__ Wp,
                                            const float* __restrict__ bias,
                                            const float* __restrict__ dinv,
                                            u16* __restrict__ outh,
                                            float* __restrict__ outf, int hidden) {
    const int lane = threadIdx.x & 63;
    const int quad = lane >> 4;
    const int l16 = lane & 15;

    const uint4* wq = (const uint4*)Wp;
    union { uint4 u; f16x8 f; } bfr[4][2];
#pragma unroll
    for (int t = 0; t < 4; ++t)
#pragma unroll
        for (int c = 0; c < 2; ++c)
            bfr[t][c].u = wq[t * 128 + c * 64 + quad * 16 + l16];
    float4 bq = ((const float4*)bias)[l16];
    float bv[4] = {bq.x, bq.y, bq.z, bq.w};

    int wave = (blockIdx.x * blockDim.x + threadIdx.x) >> 6;
    int nwaves = (gridDim.x * blockDim.x) >> 6;
    for (int chunk = wave; chunk < N_NODES / 16; chunk += nwaves) {
        int row0 = chunk * 16;
        const u16* hb = h + (size_t)row0 * 64;
        union { uint4 u; f16x8 f; } a0, a1;
        a0.u = *(const uint4*)(hb + l16 * 64 + quad * 8);
        a1.u = *(const uint4*)(hb + l16 * 64 + quad * 8 + 32);

        f32x4 acc[4] = {{0.f, 0.f, 0.f, 0.f}, {0.f, 0.f, 0.f, 0.f},
                        {0.f, 0.f, 0.f, 0.f}, {0.f, 0.f, 0.f, 0.f}};
#pragma unroll
        for (int t = 0; t < 4; ++t) {
            acc[t] = __builtin_amdgcn_mfma_f32_16x16x32_f16(a0.f, bfr[t][0].f, acc[t], 0, 0, 0);
            acc[t] = __builtin_amdgcn_mfma_f32_16x16x32_f16(a1.f, bfr[t][1].f, acc[t], 0, 0, 0);
        }
        float dv[4];
#pragma unroll
        for (int r = 0; r < 4; ++r) dv[r] = dinv[row0 + quad * 4 + r];
#pragma unroll
        for (int r = 0; r < 4; ++r) {
            int row = row0 + quad * 4 + r;
            float o[4];
#pragma unroll
            for (int t = 0; t < 4; ++t) o[t] = acc[t][r] + bv[t];
            if (hidden) {
                float dd = dv[r];
#pragma unroll
                for (int t = 0; t < 4; ++t) o[t] = fmaxf(o[t], 0.f) * dd;
                unsigned lo = (unsigned)f2h(o[0]) | ((unsigned)f2h(o[1]) << 16);
                unsigned hi = (unsigned)f2h(o[2]) | ((unsigned)f2h(o[3]) << 16);
                ((uint2*)(outh + (size_t)row * 64))[l16] = make_uint2(lo, hi);
            } else {
                ((float4*)(outf + (size_t)row * 64))[l16] =
                    make_float4(o[0], o[1], o[2], o[3]);
            }
        }
    }
}

extern "C" void kernel_launch(void* const* d_in, const int* in_sizes, int n_in,
                              void* d_out, int out_size, void* d_ws, size_t ws_size,
                              hipStream_t stream) {
    const float* z  = (const float*)d_in[0];
    const int* src  = (const int*)d_in[1];
    const int* dst  = (const int*)d_in[2];
    const float* W1 = (const float*)d_in[3];
    const float* b1 = (const float*)d_in[4];
    const float* W2 = (const float*)d_in[5];
    const float* b2 = (const float*)d_in[6];
    const float* W3 = (const float*)d_in[7];
    const float* b3 = (const float*)d_in[8];
    float* out = (float*)d_out;

    char* p = (char*)d_ws;
    float* dinv    = (float*)p;  p += (size_t)512 << 10;
    int2*  rowinfo = (int2*)p;   p += (size_t)1 << 20;                   // 800 KB used
    int*   btot    = (int*)p;    p += (size_t)4 << 10;                   // 2 KB used
    int*   ebuf    = (int*)p;    p += (size_t)N_BUCKETS * CAP_E * 4;     // 8 MB
    int*   col     = (int*)p;    p += (size_t)N_BUCKETS * CAP_C * 4;     // 12.6 MB
    u16*   hbuf    = (u16*)p;    p += (size_t)13 << 20;                  // 12.8 MB used
    u16*   buf0    = (u16*)p;    p += (size_t)13 << 20;                  // +dummy row
    u16*   buf1    = (u16*)p;    p += (size_t)13 << 20;                  // +dummy row
    u16*   wp      = (u16*)p;                                            // 24 KB

    const int gA = 6250;  // 25000 waves: exactly 1 quad per wave
    const int gM = 1563;  // 6252 waves, ~1 chunk each

    // ---- CSR build (512 buckets) + W permute (fused) + fp16 scale ----
    hipMemsetAsync(btot, 0, N_BUCKETS * sizeof(int), stream);
    k_bucket<<<BKT_BLOCKS + 3, 256, 0, stream>>>(src, dst, btot, ebuf, W1, W2, W3, wp);
    k_build<<<N_BUCKETS, 512, 0, stream>>>(btot, ebuf, col, rowinfo, dinv, z, buf0, buf1);

    // ---- 3 layers: agg (gather) + mv (MFMA matvec) ----
    k_agg<<<gA, 256, 0, stream>>>(rowinfo, col, dinv, buf0, hbuf);
    k_mv <<<gM, 256, 0, stream>>>(hbuf, wp, b1, dinv, buf1, nullptr, 1);
    k_agg<<<gA, 256, 0, stream>>>(rowinfo, col, dinv, buf1, hbuf);
    k_mv <<<gM, 256, 0, stream>>>(hbuf, wp + 4096, b2, dinv, buf0, nullptr, 1);
    k_agg<<<gA, 256, 0, stream>>>(rowinfo, col, dinv, buf0, hbuf);
    k_mv <<<gM, 256, 0, stream>>>(hbuf, wp + 8192, b3, dinv, nullptr, out, 0);
}

// Round 8
// 252.330 us; speedup vs baseline: 1.1321x; 1.0186x over previous
//
#include <hip/hip_runtime.h>
#include <hip/hip_fp16.h>

#define N_NODES 100000
#define N_EDGES 1600000
#define N_BUCKETS 512
#define BUCKET_NODES 196      // 512*196 = 100352 >= N_NODES
#define BKT_BLOCKS 512
#define CAP_E 4096            // raw edges per bucket: mean 3125
#define CAP_C 6144            // padded(8) col slots per bucket: mean ~3920
#define DUMMY N_NODES         // zero feature row (byte offset DUMMY*128)

typedef unsigned short u16;
typedef _Float16 f16x8 __attribute__((ext_vector_type(8)));
typedef float f32x4 __attribute__((ext_vector_type(4)));
typedef unsigned u32x4 __attribute__((ext_vector_type(4)));

__device__ __forceinline__ u16 f2h(float f) {
    return __half_as_ushort(__float2half_rn(f));
}

__device__ __forceinline__ void acc8v(float* acc, u32x4 q) {
#pragma unroll
    for (int i = 0; i < 4; ++i) {
        unsigned w = q[i];
        __half2 h = *reinterpret_cast<__half2*>(&w);
        float2 f = __half22float2(h);
        acc[2 * i] += f.x;
        acc[2 * i + 1] += f.y;
    }
}

__device__ __forceinline__ void acc8(float* acc, uint4 q) {
    unsigned v[4] = {q.x, q.y, q.z, q.w};
#pragma unroll
    for (int i = 0; i < 4; ++i) {
        __half2 h = *reinterpret_cast<__half2*>(&v[i]);
        float2 f = __half22float2(h);
        acc[2 * i] += f.x;
        acc[2 * i + 1] += f.y;
    }
}

// ---- phase 1: bucket edges into CONTIGUOUS per-bucket runs (R8 form).
//      Blocks >= BKT_BLOCKS instead do the one-time W fragment permute. ----
__global__ __launch_bounds__(256) void k_bucket(const int* __restrict__ src,
                                                const int* __restrict__ dst,
                                                int* __restrict__ btot,
                                                int* __restrict__ ebuf,
                                                const float* __restrict__ W1,
                                                const float* __restrict__ W2,
                                                const float* __restrict__ W3,
                                                u16* __restrict__ Wp) {
    __shared__ int cnt[N_BUCKETS], base_s[N_BUCKETS];
    if (blockIdx.x >= BKT_BLOCKS) {  // fused k_prepw
        int wb = blockIdx.x - BKT_BLOCKS;
        const float* W = wb == 0 ? W1 : (wb == 1 ? W2 : W3);
        u16* o = Wp + wb * 4096;
        for (int f = threadIdx.x; f < 4096; f += 256) {
            int j = f & 7, l16 = (f >> 3) & 15, quad = (f >> 7) & 3;
            int c = (f >> 9) & 1, t = f >> 10;
            o[f] = f2h(W[(quad * 8 + 32 * c + j) * 64 + 4 * l16 + t]);
        }
        return;
    }
    const int CS = N_EDGES / BKT_BLOCKS;  // 3125
    int t = threadIdx.x;
    int beg = blockIdx.x * CS, end = beg + CS;
    for (int i = t; i < N_BUCKETS; i += 256) cnt[i] = 0;
    __syncthreads();
    for (int e = beg + t; e < end; e += 256)
        atomicAdd(&cnt[(unsigned)dst[e] / BUCKET_NODES], 1);
    __syncthreads();
    for (int i = t; i < N_BUCKETS; i += 256) {
        base_s[i] = atomicAdd(&btot[i], cnt[i]);
        cnt[i] = 0;  // reuse as local cursor
    }
    __syncthreads();
    for (int e = beg + t; e < end; e += 256) {
        int d = dst[e], s = src[e];
        int b = (unsigned)d / BUCKET_NODES;
        int l = atomicAdd(&cnt[b], 1);
        ebuf[b * CAP_E + base_s[b] + l] = s | ((d - b * BUCKET_NODES) << 17);
    }
}

// ---- phase 2: per-bucket LDS bin; PAD-8 rows; col = byte offsets; 16-entry
//      DUMMY guard; fused xs(fp16) = z*dinv. 512x512, wave-shuffle scan. ----
__global__ __launch_bounds__(512) void k_build(const int* __restrict__ btot,
                                               const int* __restrict__ ebuf,
                                               int* __restrict__ col,
                                               int2* __restrict__ rowinfo,
                                               float* __restrict__ dinv,
                                               const float* __restrict__ z,
                                               u16* __restrict__ xs,
                                               u16* __restrict__ xs_other) {
    __shared__ int deg[BUCKET_NODES];
    __shared__ int cur[BUCKET_NODES];
    __shared__ int wsum[4];
    __shared__ int cls[CAP_C];
    int b = blockIdx.x, t = threadIdx.x;
    int nb = b * BUCKET_NODES;
    int nn = N_NODES - nb;
    if (nn > BUCKET_NODES) nn = BUCKET_NODES;
    int ne = btot[b];
    const int* eb = ebuf + b * CAP_E;

    for (int i = t; i < BUCKET_NODES; i += 512) deg[i] = 0;
    __syncthreads();
    for (int e = t; e < ne; e += 512) atomicAdd(&deg[eb[e] >> 17], 1);
    __syncthreads();

    // pad-to-8 lengths; inclusive wave-shuffle scan over 256 slots (nn<=196)
    int pv = (t < nn) ? ((deg[t] + 7) & ~7) : 0;
    int v = pv;
    int lane = t & 63, wv = t >> 6;
#pragma unroll
    for (int off = 1; off < 64; off <<= 1) {
        int u = __shfl_up(v, off, 64);
        if (lane >= off) v += u;
    }
    if (t < 256 && lane == 63) wsum[wv] = v;
    __syncthreads();
    int total = wsum[0] + wsum[1] + wsum[2] + wsum[3];
    int add = 0;
    for (int i = 0; i < wv && i < 4; ++i) add += wsum[i];
    int incl = v + add;  // inclusive scan value for slot t (t<256)

    int colbase = b * CAP_C;
    if (t < nn) {
        int off0 = incl - pv;
        cur[t] = off0;
        rowinfo[nb + t] = make_int2(colbase + off0, pv);
        dinv[nb + t] = rsqrtf((float)deg[t] + 1.0f);
    }
    __syncthreads();
    for (int i = t; i < total; i += 512) cls[i] = DUMMY << 7;  // pads pre-filled
    __syncthreads();
    for (int e = t; e < ne; e += 512) {
        int pe = eb[e];
        int l = atomicAdd(&cur[pe >> 17], 1);
        cls[l] = (pe & 0x1FFFF) << 7;  // byte offset of src row
    }
    __syncthreads();
    for (int i = t; i < total; i += 512) col[colbase + i] = cls[i];
    if (t < 16) col[colbase + total + t] = DUMMY << 7;  // guard for clamped reads

    // fused scale: xs(fp16) = z * dinv for this bucket's rows
    const float4* zz = (const float4*)(z + (size_t)nb * 64);
    uint2* xx = (uint2*)(xs + (size_t)nb * 64);
    for (int i = t; i < nn * 16; i += 512) {
        float4 vv = zz[i];
        float dd = rsqrtf((float)deg[i >> 4] + 1.0f);
        unsigned p0 = (unsigned)f2h(vv.x * dd) | ((unsigned)f2h(vv.y * dd) << 16);
        unsigned p1 = (unsigned)f2h(vv.z * dd) | ((unsigned)f2h(vv.w * dd) << 16);
        xx[i] = make_uint2(p0, p1);
    }
    if (b == 0 && t < 8) {  // zero dummy rows of both fp16 feature buffers
        ((uint4*)(xs + (size_t)N_NODES * 64))[t] = make_uint4(0, 0, 0, 0);
        ((uint4*)(xs_other + (size_t)N_NODES * 64))[t] = make_uint4(0, 0, 0, 0);
    }
}

// ---- gather-only aggregation, pad-8 rows, QUAD-node waves.
//      ALL 13 gathers (8 main + 4 tail + 1 combined-self covering 4 rows)
//      issued in ONE indivisible asm block with early-clobber dests and the
//      vmcnt(0) inside — nothing can be interleaved, so 13x4 dest VGPRs are
//      provably live and 13 lines are truly in flight per wave.
//      launch_bounds (256,2): 256-VGPR budget so the mega-asm (78 pinned
//      regs) cannot fail register allocation; 8 waves/CU x 13 lines = 104
//      outstanding lines/CU vs ~44 before.
//      h[n] = fp16( dinv[n]*(sum_{s in row(n)} xs[s] + xs[n]) ). ----
__global__ __launch_bounds__(256, 2) void k_agg(const int2* __restrict__ rowinfo,
                                                const int* __restrict__ col,
                                                const float* __restrict__ dinv,
                                                const u16* __restrict__ xs,
                                                u16* __restrict__ h) {
    const int lane = threadIdx.x & 63;
    const int eighth = lane >> 3;
    const int fh = lane & 7;
    const char* xb = (const char*)xs;
    int wave = (blockIdx.x * blockDim.x + threadIdx.x) >> 6;
    int nwaves = (gridDim.x * blockDim.x) >> 6;

    for (int n0 = wave * 4; n0 < N_NODES; n0 += nwaves * 4) {
        int u0 = __builtin_amdgcn_readfirstlane(n0);  // uniform -> s_loads below
        int2 r0 = rowinfo[u0];
        int2 r1 = rowinfo[u0 + 1];
        int2 r2 = rowinfo[u0 + 2];
        int2 r3 = rowinfo[u0 + 3];
        int it0 = r0.y >> 4, it1 = r1.y >> 4, it2 = r2.y >> 4, it3 = r3.y >> 4;
        int itm = it0 > it1 ? it0 : it1;
        if (it2 > itm) itm = it2;
        if (it3 > itm) itm = it3;

        // iter-0 cols + tail cols (guard slots make every address safe)
        int2 c0 = *(const int2*)(col + r0.x + 2 * eighth);
        int2 c1 = *(const int2*)(col + r1.x + 2 * eighth);
        int2 c2 = *(const int2*)(col + r2.x + 2 * eighth);
        int2 c3 = *(const int2*)(col + r3.x + 2 * eighth);
        int tc0 = col[r0.x + (it0 << 4) + eighth];
        int tc1 = col[r1.x + (it1 << 4) + eighth];
        int tc2 = col[r2.x + (it2 << 4) + eighth];
        int tc3 = col[r3.x + (it3 << 4) + eighth];
        float d0 = dinv[u0];
        float d1 = dinv[u0 + 1];
        float d2 = dinv[u0 + 2];
        float d3 = dinv[u0 + 3];

        const char* A0 = xb + (unsigned)c0.x + fh * 16;
        const char* A1 = xb + (unsigned)c0.y + fh * 16;
        const char* A2 = xb + (unsigned)c1.x + fh * 16;
        const char* A3 = xb + (unsigned)c1.y + fh * 16;
        const char* A4 = xb + (unsigned)c2.x + fh * 16;
        const char* A5 = xb + (unsigned)c2.y + fh * 16;
        const char* A6 = xb + (unsigned)c3.x + fh * 16;
        const char* A7 = xb + (unsigned)c3.y + fh * 16;
        const char* A8 = xb + (unsigned)tc0 + fh * 16;
        const char* A9 = xb + (unsigned)tc1 + fh * 16;
        const char* Aa = xb + (unsigned)tc2 + fh * 16;
        const char* Ab = xb + (unsigned)tc3 + fh * 16;
        const char* Ac = xb + (size_t)(u0 + (eighth & 3)) * 128 + fh * 16;

        u32x4 q0, q1, q2, q3, q4, q5, q6, q7, g0, g1, g2, g3, sf;
        asm volatile(
            "global_load_dwordx4 %0, %13, off\n\t"
            "global_load_dwordx4 %1, %14, off\n\t"
            "global_load_dwordx4 %2, %15, off\n\t"
            "global_load_dwordx4 %3, %16, off\n\t"
            "global_load_dwordx4 %4, %17, off\n\t"
            "global_load_dwordx4 %5, %18, off\n\t"
            "global_load_dwordx4 %6, %19, off\n\t"
            "global_load_dwordx4 %7, %20, off\n\t"
            "global_load_dwordx4 %8, %21, off\n\t"
            "global_load_dwordx4 %9, %22, off\n\t"
            "global_load_dwordx4 %10, %23, off\n\t"
            "global_load_dwordx4 %11, %24, off\n\t"
            "global_load_dwordx4 %12, %25, off\n\t"
            "s_waitcnt vmcnt(0)"
            : "=&v"(q0), "=&v"(q1), "=&v"(q2), "=&v"(q3),
              "=&v"(q4), "=&v"(q5), "=&v"(q6), "=&v"(q7),
              "=&v"(g0), "=&v"(g1), "=&v"(g2), "=&v"(g3), "=&v"(sf)
            : "v"(A0), "v"(A1), "v"(A2), "v"(A3), "v"(A4), "v"(A5),
              "v"(A6), "v"(A7), "v"(A8), "v"(A9), "v"(Aa), "v"(Ab), "v"(Ac)
            : "memory");
        __builtin_amdgcn_sched_barrier(0);  // consumes stay below

        float a0[8] = {0.f, 0.f, 0.f, 0.f, 0.f, 0.f, 0.f, 0.f};
        float a1[8] = {0.f, 0.f, 0.f, 0.f, 0.f, 0.f, 0.f, 0.f};
        float a2[8] = {0.f, 0.f, 0.f, 0.f, 0.f, 0.f, 0.f, 0.f};
        float a3[8] = {0.f, 0.f, 0.f, 0.f, 0.f, 0.f, 0.f, 0.f};
        if (0 < it0) { acc8v(a0, q0); acc8v(a0, q1); }
        if (0 < it1) { acc8v(a1, q2); acc8v(a1, q3); }
        if (0 < it2) { acc8v(a2, q4); acc8v(a2, q5); }
        if (0 < it3) { acc8v(a3, q6); acc8v(a3, q7); }
        if ((r0.y >> 3) & 1) acc8v(a0, g0);
        if ((r1.y >> 3) & 1) acc8v(a1, g1);
        if ((r2.y >> 3) & 1) acc8v(a2, g2);
        if ((r3.y >> 3) & 1) acc8v(a3, g3);
        if (eighth == 0) acc8v(a0, sf);
        if (eighth == 1) acc8v(a1, sf);
        if (eighth == 2) acc8v(a2, sf);
        if (eighth == 3) acc8v(a3, sf);

        // rare path: remaining 16-slot iterations (itm > 1 for ~6% of quads)
        for (int rr = 1; rr < itm; ++rr) {
            int2 e0 = *(const int2*)(col + r0.x + ((rr < it0 ? rr : 0) << 4) + 2 * eighth);
            int2 e1 = *(const int2*)(col + r1.x + ((rr < it1 ? rr : 0) << 4) + 2 * eighth);
            int2 e2 = *(const int2*)(col + r2.x + ((rr < it2 ? rr : 0) << 4) + 2 * eighth);
            int2 e3 = *(const int2*)(col + r3.x + ((rr < it3 ? rr : 0) << 4) + 2 * eighth);
            uint4 p0 = *(const uint4*)(xb + (unsigned)e0.x + fh * 16);
            uint4 p1 = *(const uint4*)(xb + (unsigned)e0.y + fh * 16);
            uint4 p2 = *(const uint4*)(xb + (unsigned)e1.x + fh * 16);
            uint4 p3 = *(const uint4*)(xb + (unsigned)e1.y + fh * 16);
            uint4 p4 = *(const uint4*)(xb + (unsigned)e2.x + fh * 16);
            uint4 p5 = *(const uint4*)(xb + (unsigned)e2.y + fh * 16);
            uint4 p6 = *(const uint4*)(xb + (unsigned)e3.x + fh * 16);
            uint4 p7 = *(const uint4*)(xb + (unsigned)e3.y + fh * 16);
            if (rr < it0) { acc8(a0, p0); acc8(a0, p1); }
            if (rr < it1) { acc8(a1, p2); acc8(a1, p3); }
            if (rr < it2) { acc8(a2, p4); acc8(a2, p5); }
            if (rr < it3) { acc8(a3, p6); acc8(a3, p7); }
        }

#pragma unroll
        for (int m = 8; m <= 32; m <<= 1) {
#pragma unroll
            for (int j = 0; j < 8; ++j) {
                a0[j] += __shfl_xor(a0[j], m, 64);
                a1[j] += __shfl_xor(a1[j], m, 64);
                a2[j] += __shfl_xor(a2[j], m, 64);
                a3[j] += __shfl_xor(a3[j], m, 64);
            }
        }
        uint4 p0, p1, p2, p3;
        u16* pp0 = (u16*)&p0;
        u16* pp1 = (u16*)&p1;
        u16* pp2 = (u16*)&p2;
        u16* pp3 = (u16*)&p3;
#pragma unroll
        for (int j = 0; j < 8; ++j) {
            pp0[j] = f2h(a0[j] * d0);
            pp1[j] = f2h(a1[j] * d1);
            pp2[j] = f2h(a2[j] * d2);
            pp3[j] = f2h(a3[j] * d3);
        }
        if (eighth == 0) ((uint4*)(h + (size_t)u0 * 64))[fh] = p0;
        if (eighth == 1) ((uint4*)(h + (size_t)(u0 + 1) * 64))[fh] = p1;
        if (eighth == 2) ((uint4*)(h + (size_t)(u0 + 2) * 64))[fh] = p2;
        if (eighth == 3) ((uint4*)(h + (size_t)(u0 + 3) * 64))[fh] = p3;
    }
}

// ---- MFMA matvec: out = epi( h @ W + b ), 16-row chunks per wave. ----
__global__ __launch_bounds__(256) void k_mv(const u16* __restrict__ h,
                                            const u16* __restrict__ Wp,
                                            const float* __restrict__ bias,
                                            const float* __restrict__ dinv,
                                            u16* __restrict__ outh,
                                            float* __restrict__ outf, int hidden) {
    const int lane = threadIdx.x & 63;
    const int quad = lane >> 4;
    const int l16 = lane & 15;

    const uint4* wq = (const uint4*)Wp;
    union { uint4 u; f16x8 f; } bfr[4][2];
#pragma unroll
    for (int t = 0; t < 4; ++t)
#pragma unroll
        for (int c = 0; c < 2; ++c)
            bfr[t][c].u = wq[t * 128 + c * 64 + quad * 16 + l16];
    float4 bq = ((const float4*)bias)[l16];
    float bv[4] = {bq.x, bq.y, bq.z, bq.w};

    int wave = (blockIdx.x * blockDim.x + threadIdx.x) >> 6;
    int nwaves = (gridDim.x * blockDim.x) >> 6;
    for (int chunk = wave; chunk < N_NODES / 16; chunk += nwaves) {
        int row0 = chunk * 16;
        const u16* hb = h + (size_t)row0 * 64;
        union { uint4 u; f16x8 f; } a0, a1;
        a0.u = *(const uint4*)(hb + l16 * 64 + quad * 8);
        a1.u = *(const uint4*)(hb + l16 * 64 + quad * 8 + 32);

        f32x4 acc[4] = {{0.f, 0.f, 0.f, 0.f}, {0.f, 0.f, 0.f, 0.f},
                        {0.f, 0.f, 0.f, 0.f}, {0.f, 0.f, 0.f, 0.f}};
#pragma unroll
        for (int t = 0; t < 4; ++t) {
            acc[t] = __builtin_amdgcn_mfma_f32_16x16x32_f16(a0.f, bfr[t][0].f, acc[t], 0, 0, 0);
            acc[t] = __builtin_amdgcn_mfma_f32_16x16x32_f16(a1.f, bfr[t][1].f, acc[t], 0, 0, 0);
        }
        float dv[4];
#pragma unroll
        for (int r = 0; r < 4; ++r) dv[r] = dinv[row0 + quad * 4 + r];
#pragma unroll
        for (int r = 0; r < 4; ++r) {
            int row = row0 + quad * 4 + r;
            float o[4];
#pragma unroll
            for (int t = 0; t < 4; ++t) o[t] = acc[t][r] + bv[t];
            if (hidden) {
                float dd = dv[r];
#pragma unroll
                for (int t = 0; t < 4; ++t) o[t] = fmaxf(o[t], 0.f) * dd;
                unsigned lo = (unsigned)f2h(o[0]) | ((unsigned)f2h(o[1]) << 16);
                unsigned hi = (unsigned)f2h(o[2]) | ((unsigned)f2h(o[3]) << 16);
                ((uint2*)(outh + (size_t)row * 64))[l16] = make_uint2(lo, hi);
            } else {
                ((float4*)(outf + (size_t)row * 64))[l16] =
                    make_float4(o[0], o[1], o[2], o[3]);
            }
        }
    }
}

extern "C" void kernel_launch(void* const* d_in, const int* in_sizes, int n_in,
                              void* d_out, int out_size, void* d_ws, size_t ws_size,
                              hipStream_t stream) {
    const float* z  = (const float*)d_in[0];
    const int* src  = (const int*)d_in[1];
    const int* dst  = (const int*)d_in[2];
    const float* W1 = (const float*)d_in[3];
    const float* b1 = (const float*)d_in[4];
    const float* W2 = (const float*)d_in[5];
    const float* b2 = (const float*)d_in[6];
    const float* W3 = (const float*)d_in[7];
    const float* b3 = (const float*)d_in[8];
    float* out = (float*)d_out;

    char* p = (char*)d_ws;
    float* dinv    = (float*)p;  p += (size_t)512 << 10;
    int2*  rowinfo = (int2*)p;   p += (size_t)1 << 20;                   // 800 KB used
    int*   btot    = (int*)p;    p += (size_t)4 << 10;                   // 2 KB used
    int*   ebuf    = (int*)p;    p += (size_t)N_BUCKETS * CAP_E * 4;     // 8 MB
    int*   col     = (int*)p;    p += (size_t)N_BUCKETS * CAP_C * 4;     // 12.6 MB
    u16*   hbuf    = (u16*)p;    p += (size_t)13 << 20;                  // 12.8 MB used
    u16*   buf0    = (u16*)p;    p += (size_t)13 << 20;                  // +dummy row
    u16*   buf1    = (u16*)p;    p += (size_t)13 << 20;                  // +dummy row
    u16*   wp      = (u16*)p;                                            // 24 KB

    const int gA = 6250;  // 25000 waves: exactly 1 quad per wave
    const int gM = 1563;  // 6252 waves, ~1 chunk each

    // ---- CSR build (512 buckets) + W permute (fused) + fp16 scale ----
    hipMemsetAsync(btot, 0, N_BUCKETS * sizeof(int), stream);
    k_bucket<<<BKT_BLOCKS + 3, 256, 0, stream>>>(src, dst, btot, ebuf, W1, W2, W3, wp);
    k_build<<<N_BUCKETS, 512, 0, stream>>>(btot, ebuf, col, rowinfo, dinv, z, buf0, buf1);

    // ---- 3 layers: agg (gather) + mv (MFMA matvec) ----
    k_agg<<<gA, 256, 0, stream>>>(rowinfo, col, dinv, buf0, hbuf);
    k_mv <<<gM, 256, 0, stream>>>(hbuf, wp, b1, dinv, buf1, nullptr, 1);
    k_agg<<<gA, 256, 0, stream>>>(rowinfo, col, dinv, buf1, hbuf);
    k_mv <<<gM, 256, 0, stream>>>(hbuf, wp + 4096, b2, dinv, buf0, nullptr, 1);
    k_agg<<<gA, 256, 0, stream>>>(rowinfo, col, dinv, buf0, hbuf);
    k_mv <<<gM, 256, 0, stream>>>(hbuf, wp + 8192, b3, dinv, nullptr, out, 0);
}